// Round 1
// 426.805 us; speedup vs baseline: 1.0711x; 1.0711x over previous
//
#include <hip/hip_runtime.h>
#include <hip/hip_bf16.h>
#include <stdint.h>

// StaticGraphLSTMCell: B=512, N=21, I=256, H=1024, NT=5
// out = [hy (B*N*H) | cy (B*N*H) | gx_out (N*N)] fp32
//
// ws layout (bytes):
//   Wc   bf16 [5][4096][1280]   @ 0          (52,428,800)
//   Xc   bf16 [21][512][1280]   @ 52,428,800 (27,525,120)
//   gates bf16 [512][21][4096]  @ 79,953,920 (88,080,384)
//   gx   f32  [21][21]          @ 168,034,304 (1,764)

typedef __bf16 bf16_t;
typedef __bf16 bf16x8 __attribute__((ext_vector_type(8)));
typedef float f32x4 __attribute__((ext_vector_type(4)));

#define NB 512
#define NN 21
#define NI 256
#define NH 1024
#define KDIM 1280
#define ODIM 4096
#define BNH (512ull * 21 * 1024)

__device__ inline void gld16(const void* g, const void* l) {
  __builtin_amdgcn_global_load_lds(
      (const __attribute__((address_space(1))) unsigned int*)g,
      (__attribute__((address_space(3))) unsigned int*)l, 16, 0, 0);
}

__device__ inline float sigmoid_fast(float x) {
  return 1.0f / (1.0f + __expf(-x));
}
__device__ inline float tanh_fast(float x) {
  float ax = fabsf(x);
  float e = __expf(2.0f * ax);  // inf-safe: 2/(inf+1)=0 -> 1
  float t = 1.0f - 2.0f / (e + 1.0f);
  return copysignf(t, x);
}

// raw workgroup barrier: no vmcnt drain, but a compile-time memory fence so
// LDS reads/writes cannot be moved across it by the scheduler.
__device__ inline void wg_barrier() {
  asm volatile("" ::: "memory");
  __builtin_amdgcn_s_barrier();
  asm volatile("" ::: "memory");
}

// ---- merged prep: pack weights, pack activations, gx normalize -------------
// blocks [0, 12800): pack_w ; [12800, 19520): pack_x ; 19520: gx
__global__ __launch_bounds__(256) void pack_all(
    const float* __restrict__ wih, const float* __restrict__ whh,
    const float* __restrict__ input, const float* __restrict__ hx,
    const float* __restrict__ G, bf16_t* __restrict__ Wc,
    bf16_t* __restrict__ Xc, float* __restrict__ gxw,
    float* __restrict__ gxout) {
  const int bx = blockIdx.x;
  const int tid = threadIdx.x;
  if (bx < 12800) {
    // Wc[row][k] = k<256 ? wih : whh   (row = tau*4096 + o)
    int c = bx * 256 + tid;  // chunk of 8; total 3,276,800
    int k8 = c % (KDIM / 8);
    int row = c / (KDIM / 8);
    int k = k8 * 8;
    const float* src = (k < NI) ? (wih + (size_t)row * NI + k)
                                : (whh + (size_t)row * NH + (k - NI));
    float4 a = *(const float4*)src;
    float4 b = *(const float4*)(src + 4);
    bf16x8 o;
    o[0] = (bf16_t)a.x; o[1] = (bf16_t)a.y; o[2] = (bf16_t)a.z; o[3] = (bf16_t)a.w;
    o[4] = (bf16_t)b.x; o[5] = (bf16_t)b.y; o[6] = (bf16_t)b.z; o[7] = (bf16_t)b.w;
    *(bf16x8*)&Wc[(size_t)c * 8] = o;
  } else if (bx < 19520) {
    // Xc[n][b][k] = k<256 ? input : hx
    int c = (bx - 12800) * 256 + tid;  // total 1,720,320
    int k8 = c % (KDIM / 8);
    int rest = c / (KDIM / 8);  // n*512 + b
    int n = rest / NB;
    int b = rest % NB;
    int k = k8 * 8;
    const float* src = (k < NI) ? (input + ((size_t)b * NN + n) * NI + k)
                                : (hx + ((size_t)b * NN + n) * NH + (k - NI));
    float4 a = *(const float4*)src;
    float4 d = *(const float4*)(src + 4);
    bf16x8 o;
    o[0] = (bf16_t)a.x; o[1] = (bf16_t)a.y; o[2] = (bf16_t)a.z; o[3] = (bf16_t)a.w;
    o[4] = (bf16_t)d.x; o[5] = (bf16_t)d.y; o[6] = (bf16_t)d.z; o[7] = (bf16_t)d.w;
    *(bf16x8*)&Xc[(size_t)c * 8] = o;
  } else {
    // gx: gxw = normalize(G); gxout = normalize(gxw)
    int m = tid;
    if (m < NN) {
      float s = 0.f;
      for (int j = 0; j < NN; j++) s += fabsf(G[m * NN + j]);
      s = fmaxf(s, 1e-12f);
      float row[NN];
      float s2 = 0.f;
      for (int j = 0; j < NN; j++) {
        row[j] = G[m * NN + j] / s;
        s2 += fabsf(row[j]);
      }
      s2 = fmaxf(s2, 1e-12f);
      for (int j = 0; j < NN; j++) {
        gxw[m * NN + j] = row[j];
        gxout[m * NN + j] = row[j] / s2;
      }
    }
  }
}

// ---- GEMM: 256x256 tile, BK=32, 8 waves (2M x 4N), 4-slot LDS pipeline -----
// per node n (blockIdx.z): gates[b][n][o] = Xc[n][b][:] . Wc[tau][o][:] + bias
//
// LDS: 4 slots x (A[256][32] + B[256][32]) bf16 = 4 x 32 KiB = 128 KiB.
// Chunk swizzle (16B chunks, 4 per row): phys p = logical col16 ^ ((row>>1)&3)
//   -> ds_read_b128 fragment reads become 2-way (free) instead of 8-way.
//   Applied to the GLOBAL source address at stage time (gld_lds writes
//   linearly) and to the ds_read address (both-sides-or-neither).
// Pipeline: while computing K-tile t (2 phases x 16 MFMA/wave), stage K-tile
// t+2 into slot (t+2)&3 (A in phase 0, B in phase 1). End of tile:
// s_waitcnt vmcnt(4) (never 0 in steady state) -> K-tile t+1 fully landed.
__global__ __launch_bounds__(512, 2) void gemm_bt(
    const bf16_t* __restrict__ Xc, const bf16_t* __restrict__ Wc,
    const float* __restrict__ bhh, const int* __restrict__ node_types,
    bf16_t* __restrict__ gates) {
  __shared__ char lds[4 * 32768];

  const int n = blockIdx.z;
  const int tau = node_types[n];
  const bf16_t* A = Xc + (size_t)n * NB * KDIM;
  const bf16_t* Bw = Wc + (size_t)tau * ODIM * KDIM;

  const int tid = threadIdx.x;
  const int lane = tid & 63;
  const int w = tid >> 6;          // 0..7
  const int wm = (w & 1) * 128;    // wave M offset
  const int wn = (w >> 1) * 64;    // wave N offset
  const int r = lane & 15;
  const int quad = lane >> 4;

  const int m0 = blockIdx.y * 256;
  const int n0 = blockIdx.x * 256;

  // fragment read offsets (swizzled); ga/gb invariant over frag index i/j
  const int ga = ((wm + r) >> 1) & 3;
  const int gb = ((wn + r) >> 1) & 3;
  const int aoff = (wm + r) * 64 + ((quad ^ ga) * 16);
  const int boff = 16384 + (wn + r) * 64 + ((quad ^ gb) * 16);

  // staging: wave-contiguous chunks (lane l writes chunk base+l -> linear)
  const int ca = w * 128 + lane;  // q0 chunk
  const int cb = ca + 64;         // q1 chunk
  const int rA0 = ca >> 2, cA0 = (ca & 3) ^ ((rA0 >> 1) & 3);
  const int rA1 = cb >> 2, cA1 = (cb & 3) ^ ((rA1 >> 1) & 3);
  const bf16_t* gA0 = A + (size_t)(m0 + rA0) * KDIM + cA0 * 8;
  const bf16_t* gA1 = A + (size_t)(m0 + rA1) * KDIM + cA1 * 8;
  const bf16_t* gB0 = Bw + (size_t)(n0 + rA0) * KDIM + cA0 * 8;
  const bf16_t* gB1 = Bw + (size_t)(n0 + rA1) * KDIM + cA1 * 8;
  const int dA0 = ca * 16, dA1 = cb * 16;

  f32x4 acc[8][4];
#pragma unroll
  for (int i = 0; i < 8; i++)
#pragma unroll
    for (int j = 0; j < 4; j++) acc[i][j] = {0.f, 0.f, 0.f, 0.f};

  // prologue: stage K-tiles 0 (slot0) and 1 (slot1)
  {
    char* L0 = lds;
    char* L1 = lds + 32768;
    gld16(gA0, L0 + dA0);          gld16(gA1, L0 + dA1);
    gld16(gB0, L0 + 16384 + dA0);  gld16(gB1, L0 + 16384 + dA1);
    gld16(gA0 + 32, L1 + dA0);         gld16(gA1 + 32, L1 + dA1);
    gld16(gB0 + 32, L1 + 16384 + dA0); gld16(gB1 + 32, L1 + 16384 + dA1);
    asm volatile("s_waitcnt vmcnt(4)" ::: "memory");  // tile 0 landed
    wg_barrier();
  }

  for (int t = 0; t < 40; ++t) {
    const char* P = lds + (t & 3) * 32768;
    char* Wd = lds + ((t + 2) & 3) * 32768;
    const bool st = (t < 38);
    const int kk = (t + 2) * 32;
    bf16x8 a0[4], a1[4], b0[4];

    // ---- phase 0: rows wm..wm+63, all 4 B frags
#pragma unroll
    for (int i = 0; i < 4; i++) a0[i] = *(const bf16x8*)(P + aoff + i * 1024);
#pragma unroll
    for (int j = 0; j < 4; j++) b0[j] = *(const bf16x8*)(P + boff + j * 1024);
    if (st) { gld16(gA0 + kk, Wd + dA0); gld16(gA1 + kk, Wd + dA1); }
    wg_barrier();
    asm volatile("s_waitcnt lgkmcnt(0)" ::: "memory");
    __builtin_amdgcn_sched_barrier(0);
    __builtin_amdgcn_s_setprio(1);
#pragma unroll
    for (int i = 0; i < 4; i++)
#pragma unroll
      for (int j = 0; j < 4; j++)
        acc[i][j] = __builtin_amdgcn_mfma_f32_16x16x32_bf16(a0[i], b0[j], acc[i][j], 0, 0, 0);
    __builtin_amdgcn_s_setprio(0);
    wg_barrier();

    // ---- phase 1: rows wm+64..wm+127, reuse B frags
#pragma unroll
    for (int i = 0; i < 4; i++) a1[i] = *(const bf16x8*)(P + aoff + 4096 + i * 1024);
    if (st) { gld16(gB0 + kk, Wd + 16384 + dA0); gld16(gB1 + kk, Wd + 16384 + dA1); }
    wg_barrier();
    asm volatile("s_waitcnt lgkmcnt(0)" ::: "memory");
    __builtin_amdgcn_sched_barrier(0);
    __builtin_amdgcn_s_setprio(1);
#pragma unroll
    for (int i = 0; i < 4; i++)
#pragma unroll
      for (int j = 0; j < 4; j++)
        acc[4 + i][j] = __builtin_amdgcn_mfma_f32_16x16x32_bf16(a1[i], b0[j], acc[4 + i][j], 0, 0, 0);
    __builtin_amdgcn_s_setprio(0);
    // end-of-tile: ensure K-tile t+1 fully staged before anyone reads it
    if (t < 38)       asm volatile("s_waitcnt vmcnt(4)" ::: "memory");
    else if (t == 38) asm volatile("s_waitcnt vmcnt(0)" ::: "memory");
    wg_barrier();
  }

  float bv[4];
#pragma unroll
  for (int j = 0; j < 4; j++) bv[j] = bhh[tau * ODIM + n0 + wn + j * 16 + r];
#pragma unroll
  for (int i = 0; i < 8; i++) {
    int brow = m0 + wm + i * 16 + quad * 4;
#pragma unroll
    for (int j = 0; j < 4; j++) {
      int o = n0 + wn + j * 16 + r;
#pragma unroll
      for (int reg = 0; reg < 4; reg++) {
        int b = brow + reg;
        gates[((size_t)b * NN + n) * ODIM + o] = (bf16_t)(acc[i][j][reg] + bv[j]);
      }
    }
  }
}

// ---- fused mix + pointwise LSTM --------------------------------------------
// block = (h-chunk of 256, b). Stage gates[b][n][g*1024+h0..+255] for all
// n,g in LDS (43 KB); each thread owns one h; accumulate the 21-node mix in
// f32 (gx read via wave-uniform scalar loads), then LSTM pointwise -> hy/cy.
template <int M0C, int CH>
__device__ inline void mix_chunk(const bf16_t (*gs)[4][256],
                                 const float* __restrict__ gx,
                                 const float* __restrict__ cx,
                                 float* __restrict__ out, int b, int h, int tid,
                                 bool cmask) {
  float a[CH][4];
#pragma unroll
  for (int mm = 0; mm < CH; mm++) {
    a[mm][0] = 0.f; a[mm][1] = 0.f; a[mm][2] = 0.f; a[mm][3] = 0.f;
  }
  for (int nn = 0; nn < NN; nn++) {
    float v0 = (float)gs[nn][0][tid];
    float v1 = (float)gs[nn][1][tid];
    float v2 = (float)gs[nn][2][tid];
    float v3 = (float)gs[nn][3][tid];
#pragma unroll
    for (int mm = 0; mm < CH; mm++) {
      float wgt = gx[(M0C + mm) * NN + nn];  // wave-uniform -> SGPR
      a[mm][0] = fmaf(wgt, v0, a[mm][0]);
      a[mm][1] = fmaf(wgt, v1, a[mm][1]);
      a[mm][2] = fmaf(wgt, v2, a[mm][2]);
      a[mm][3] = fmaf(wgt, v3, a[mm][3]);
    }
  }
#pragma unroll
  for (int mm = 0; mm < CH; mm++) {
    int m = M0C + mm;
    size_t off = ((size_t)b * NN + m) * NH + h;
    float c0 = cx[off];
    float ig = sigmoid_fast(a[mm][0]);
    float fg = sigmoid_fast(a[mm][1]);
    float cg = tanh_fast(a[mm][2]);
    float og = sigmoid_fast(a[mm][3]);
    float c = cmask ? fmaf(fg, c0, ig * cg) : c0;
    out[off] = og * tanh_fast(c);
    out[BNH + off] = c;
  }
}

__global__ __launch_bounds__(256) void mix_lstm(const bf16_t* __restrict__ gates,
                                                const float* __restrict__ gx,
                                                const float* __restrict__ cx,
                                                const int* __restrict__ t_ptr,
                                                float* __restrict__ out) {
  __shared__ bf16_t gs[NN][4][256];  // 43,008 B
  const int tid = threadIdx.x;
  const int b = blockIdx.y;
  const int h0 = blockIdx.x * 256;
  const size_t gb = (size_t)b * NN * ODIM;
  // stage: 21 n x 4 gates x 32 bf16x8 chunks = 2688
  for (int i = tid; i < NN * 4 * 32; i += 256) {
    int nn = i >> 7;
    int rem = i & 127;
    int g = rem >> 5;
    int c = rem & 31;
    *(bf16x8*)&gs[nn][g][c * 8] =
        *(const bf16x8*)&gates[gb + (size_t)nn * ODIM + g * NH + h0 + c * 8];
  }
  __syncthreads();

  const int h = h0 + tid;
  const float tf = (float)(t_ptr[0] + 1);
  float phase = floorf((float)h / 1023.0f * 8.0f + 1.0f);  // 1..9
  bool cmask = fmodf(tf, phase) < 0.01f;

  mix_chunk<0, 11>(gs, gx, cx, out, b, h, tid, cmask);
  mix_chunk<11, 10>(gs, gx, cx, out, b, h, tid, cmask);
}

extern "C" void kernel_launch(void* const* d_in, const int* in_sizes, int n_in,
                              void* d_out, int out_size, void* d_ws, size_t ws_size,
                              hipStream_t stream) {
  const float* input = (const float*)d_in[0];
  const float* hx = (const float*)d_in[1];
  const float* cx = (const float*)d_in[2];
  const float* G = (const float*)d_in[3];
  const float* wih = (const float*)d_in[4];
  const float* whh = (const float*)d_in[5];
  const float* bhh = (const float*)d_in[6];
  const int* node_types = (const int*)d_in[7];
  const int* t = (const int*)d_in[8];
  float* out = (float*)d_out;

  char* ws = (char*)d_ws;
  bf16_t* Wc = (bf16_t*)ws;
  bf16_t* Xc = (bf16_t*)(ws + 52428800);
  bf16_t* gates = (bf16_t*)(ws + 79953920);
  float* gxw = (float*)(ws + 168034304);

  pack_all<<<19521, 256, 0, stream>>>(wih, whh, input, hx, G, Wc, Xc, gxw,
                                      out + 2 * BNH);
  dim3 gg(ODIM / 256, NB / 256, NN);  // (16, 2, 21)
  gemm_bt<<<gg, 512, 0, stream>>>(Xc, Wc, bhh, node_types, gates);
  dim3 gm(NH / 256, NB);  // (4, 512)
  mix_lstm<<<gm, 256, 0, stream>>>(gates, gxw, cx, t, out);
}